// Round 2
// baseline (584.435 us; speedup 1.0000x reference)
//
#include <hip/hip_runtime.h>

// Sparse 3D conv (Cin=1, Cout=16), rulebook form:
//   out[out_idx[m], c] += feats[in_idx[m]] * weight[k_idx[m], c]
//
// Structure exploited: k_idx is sorted (27 concatenated segments) and
// out_idx is strictly increasing within each segment. So a contiguous
// output tile [o0, o0+T) receives a contiguous run of entries from each
// segment (found by binary search). Accumulate in LDS (ds_add_f32),
// write each tile exactly once (coalesced float4) -> no global atomics,
// no output memset.

#define TILE 512
#define NK 27

__device__ __forceinline__ int lower_bound_i32(const int* __restrict__ a,
                                               int lo, int hi, int val) {
    while (lo < hi) {
        int mid = (lo + hi) >> 1;
        if (a[mid] < val) lo = mid + 1; else hi = mid;
    }
    return lo;
}

// Segment boundaries: ks[t] = first m with k_idx[m] >= t, ks[27] = M.
__global__ void k_bounds_kernel(const int* __restrict__ k_idx, int M,
                                int* __restrict__ ks) {
    int t = threadIdx.x;
    if (t <= NK) ks[t] = lower_bound_i32(k_idx, 0, M, t);
}

__global__ __launch_bounds__(256, 4) void sparse_conv_tiled(
    const float* __restrict__ feats,
    const float* __restrict__ weight,
    const int* __restrict__ in_idx,
    const int* __restrict__ out_idx,
    const int* __restrict__ ks,
    float* __restrict__ out,
    int n_out) {
    __shared__ float tile[TILE * 16];
    __shared__ int lo_s[NK], hi_s[NK], pre_s[NK + 1];

    const int tid = threadIdx.x;
    const int o0 = blockIdx.x * TILE;
    const int rows = min(TILE, n_out - o0);

    // Zero the LDS tile (vectorized).
    float4* t4 = (float4*)tile;
    for (int i = tid; i < TILE * 4; i += 256)
        t4[i] = make_float4(0.f, 0.f, 0.f, 0.f);

    // Per-segment run [lo, hi) of entries whose out_idx falls in the tile.
    // Wave 0 does the 27 lower bounds, wave 1 the 27 upper bounds.
    if (tid < NK) {
        lo_s[tid] = lower_bound_i32(out_idx, ks[tid], ks[tid + 1], o0);
    } else if (tid >= 64 && tid < 64 + NK) {
        int k = tid - 64;
        hi_s[k] = lower_bound_i32(out_idx, ks[k], ks[k + 1], o0 + rows);
    }
    __syncthreads();

    if (tid == 0) {
        int s = 0;
        for (int k = 0; k < NK; ++k) { pre_s[k] = s; s += hi_s[k] - lo_s[k]; }
        pre_s[NK] = s;
    }
    __syncthreads();

    const int E = pre_s[NK];

    // One thread per (entry, channel); 16 consecutive lanes = one entry.
    for (int e16 = tid; e16 < E * 16; e16 += 256) {
        int e = e16 >> 4;
        int c = e16 & 15;
        int k = 0;
        while (pre_s[k + 1] <= e) ++k;      // <=27 iters, wave-coherent
        int m = lo_s[k] + (e - pre_s[k]);
        int i = in_idx[m];
        int o = out_idx[m];
        float v = feats[i] * weight[k * 16 + c];
        atomicAdd(&tile[(o - o0) * 16 + c], v);   // ds_add_f32
    }
    __syncthreads();

    // Coalesced tile writeback (every row written -> no memset needed).
    float4* out4 = (float4*)(out + (size_t)o0 * 16);
    for (int i = tid; i < rows * 4; i += 256)
        out4[i] = t4[i];
}

extern "C" void kernel_launch(void* const* d_in, const int* in_sizes, int n_in,
                              void* d_out, int out_size, void* d_ws, size_t ws_size,
                              hipStream_t stream) {
    const float* feats   = (const float*)d_in[0];
    const float* weight  = (const float*)d_in[1];
    const int*   in_idx  = (const int*)d_in[2];
    const int*   out_idx = (const int*)d_in[3];
    const int*   k_idx   = (const int*)d_in[4];
    float*       out     = (float*)d_out;

    const int M = in_sizes[2];          // rulebook length
    const int n_out = out_size / 16;    // output rows

    int* ks = (int*)d_ws;               // 28 ints of scratch

    k_bounds_kernel<<<1, 32, 0, stream>>>(k_idx, M, ks);

    const int grid = (n_out + TILE - 1) / TILE;
    sparse_conv_tiled<<<grid, 256, 0, stream>>>(
        feats, weight, in_idx, out_idx, ks, out, n_out);
}

// Round 3
// 359.265 us; speedup vs baseline: 1.6268x; 1.6268x over previous
//
#include <hip/hip_runtime.h>

// Sparse 3D conv (Cin=1, Cout=16), rulebook form:
//   out[out_idx[m], c] += feats[in_idx[m]] * weight[k_idx[m], c]
//
// k_idx is sorted (27 segments); out_idx strictly increasing within each
// segment. Per output tile [o0,o0+TILE): each segment contributes one
// contiguous run (binary search). Accumulate in an LDS tile via
// ds_add_f32 with k wave-uniform (wave w handles segments w, w+4, ...),
// so no per-element segment search and no prefix sum. Tile written once,
// fully coalesced -> no global atomics, no output memset.

#define TILE 512
#define NK 27

__device__ __forceinline__ int lower_bound_i32(const int* __restrict__ a,
                                               int lo, int hi, int val) {
    while (lo < hi) {
        int mid = (lo + hi) >> 1;
        if (a[mid] < val) lo = mid + 1; else hi = mid;
    }
    return lo;
}

// ks[t] = first m with k_idx[m] >= t; ks[27] = M.
__global__ void k_bounds_kernel(const int* __restrict__ k_idx, int M,
                                int* __restrict__ ks) {
    int t = threadIdx.x;
    if (t <= NK) ks[t] = lower_bound_i32(k_idx, 0, M, t);
}

__global__ __launch_bounds__(256, 4) void sparse_conv_tiled(
    const float* __restrict__ feats,
    const float* __restrict__ weight,
    const int* __restrict__ in_idx,
    const int* __restrict__ out_idx,
    const int* __restrict__ ks,
    float* __restrict__ out,
    int n_out) {
    __shared__ float tile[TILE * 16];   // 32 KB -> 4 blocks/CU
    __shared__ int lo_s[NK], hi_s[NK];

    const int tid = threadIdx.x;
    const int o0 = blockIdx.x * TILE;
    const int rows = min(TILE, n_out - o0);

    // Zero the LDS tile (vectorized).
    float4* t4 = (float4*)tile;
    for (int i = tid; i < TILE * 4; i += 256)
        t4[i] = make_float4(0.f, 0.f, 0.f, 0.f);

    // Per-segment run [lo, hi) of entries with out_idx in the tile.
    if (tid < NK) {
        lo_s[tid] = lower_bound_i32(out_idx, ks[tid], ks[tid + 1], o0);
    } else if (tid >= 64 && tid < 64 + NK) {
        int k = tid - 64;
        hi_s[k] = lower_bound_i32(out_idx, ks[k], ks[k + 1], o0 + rows);
    }
    __syncthreads();

    const int wave = tid >> 6;
    const int lane = tid & 63;
    const int c = lane & 15;            // channel: invariant under j += 64

    // Wave-uniform k: no per-element segment search, weight hoisted.
    for (int k = wave; k < NK; k += 4) {
        const int lo = lo_s[k];
        const int cnt = hi_s[k] - lo;
        if (cnt <= 0) continue;
        const float w = weight[k * 16 + c];
        for (int j = lane; j < cnt * 16; j += 64) {
            int m = lo + (j >> 4);
            int i = in_idx[m];          // 16-lane broadcast, L1
            int o = out_idx[m];
            atomicAdd(&tile[(o - o0) * 16 + c], feats[i] * w);  // ds_add_f32
        }
    }
    __syncthreads();

    // Coalesced tile writeback (every row written -> no memset needed).
    float4* out4 = (float4*)(out + (size_t)o0 * 16);
    for (int i = tid; i < rows * 4; i += 256)
        out4[i] = t4[i];
}

extern "C" void kernel_launch(void* const* d_in, const int* in_sizes, int n_in,
                              void* d_out, int out_size, void* d_ws, size_t ws_size,
                              hipStream_t stream) {
    const float* feats   = (const float*)d_in[0];
    const float* weight  = (const float*)d_in[1];
    const int*   in_idx  = (const int*)d_in[2];
    const int*   out_idx = (const int*)d_in[3];
    const int*   k_idx   = (const int*)d_in[4];
    float*       out     = (float*)d_out;

    const int M = in_sizes[2];          // rulebook length
    const int n_out = out_size / 16;    // output rows

    int* ks = (int*)d_ws;               // 28 ints of scratch

    k_bounds_kernel<<<1, 32, 0, stream>>>(k_idx, M, ks);

    const int grid = (n_out + TILE - 1) / TILE;
    sparse_conv_tiled<<<grid, 256, 0, stream>>>(
        feats, weight, in_idx, out_idx, ks, out, n_out);
}